// Round 4
// baseline (372.863 us; speedup 1.0000x reference)
//
#include <hip/hip_runtime.h>
#include <hip/hip_cooperative_groups.h>
#include <hip/hip_bf16.h>
#include <math.h>

namespace cg = cooperative_groups;

// Problem constants (B,F,H,E,O) = (512,512,512,8,512); all dims 512, E=8.
enum { NBLK = 256 };

typedef __attribute__((ext_vector_type(8))) short short8;
typedef __attribute__((ext_vector_type(4))) float floatx4;

static __device__ __forceinline__ unsigned short f2bf(float f) {
  unsigned u = __float_as_uint(f);
  u += 0x7fffu + ((u >> 16) & 1u);
  return (unsigned short)(u >> 16);
}
static __device__ __forceinline__ float bf2f(unsigned short h) {
  return __uint_as_float(((unsigned)h) << 16);
}
static __device__ __forceinline__ float elu1(float v) {
  return v > 0.f ? v : (__expf(v) - 1.f);
}

// async global->LDS 16B copy (wave-uniform LDS base + lane*16 scatter)
typedef __attribute__((address_space(1))) const unsigned int gu32;
typedef __attribute__((address_space(3))) unsigned int lu32;
static __device__ __forceinline__ void gld16(const unsigned short* g,
                                             unsigned short* l) {
  __builtin_amdgcn_global_load_lds((gu32*)g, (lu32*)l, 16, 0, 0);
}

struct Params {
  const float* x; const float* gw0; const float* gb0;
  const float* gw1; const float* gb1; const float* gw2; const float* gb2;
  const float* a0; const float* b0; const float* a1; const float* b1;
  const float* a2; const float* b2;
  float* out;
  unsigned short* xb; unsigned short* gw0b; unsigned short* gw1b;
  unsigned short* G0; unsigned short* G1; unsigned short* H1;
  unsigned short* H2;
  float* gates;
};

// ---- S0: convert x, gw0, gw1 (262144 elems each = 65536 float4 = 1/thread) --
static __device__ __forceinline__ void cvt_body(const Params& pr, int blk,
                                                int tid) {
  int gt = blk * 256 + tid;
  {
    float4 v = ((const float4*)pr.x)[gt];
    ushort4 o = {f2bf(v.x), f2bf(v.y), f2bf(v.z), f2bf(v.w)};
    *(ushort4*)(pr.xb + 4 * (size_t)gt) = o;
  }
  {
    float4 v = ((const float4*)pr.gw0)[gt];
    ushort4 o = {f2bf(v.x), f2bf(v.y), f2bf(v.z), f2bf(v.w)};
    *(ushort4*)(pr.gw0b + 4 * (size_t)gt) = o;
  }
  {
    float4 v = ((const float4*)pr.gw1)[gt];
    ushort4 o = {f2bf(v.x), f2bf(v.y), f2bf(v.z), f2bf(v.w)};
    *(ushort4*)(pr.gw1b + 4 * (size_t)gt) = o;
  }
}

// ---- stage a 32-row x 512-col bf16 panel into LDS via async 16B copies -----
static __device__ __forceinline__ void stage_panel(const unsigned short* src,
                                                   unsigned short* lds,
                                                   int row0, int tid) {
#pragma unroll
  for (int i = 0; i < 8; i++) {
    int c = tid + i * 256;
    int r = c >> 6;
    gld16(&src[(size_t)(row0 + r) * 512 + (c & 63) * 8], &lds[(c & ~63) * 8]);
  }
}

// ---- gating layer tile: C[m0:32, n0:32] = elu(A @ W^T + bias), K=512 -------
static __device__ __forceinline__ void gating_stage(
    const unsigned short* A, const unsigned short* W, const float* bias,
    unsigned short* C, unsigned short* As, unsigned short* Ws, int tid, int m0,
    int n0, int wm, int wn, int lr, int lk) {
  stage_panel(A, As, m0, tid);
  stage_panel(W, Ws, n0, tid);
  __syncthreads();
  floatx4 a0 = {0.f, 0.f, 0.f, 0.f}, a1 = {0.f, 0.f, 0.f, 0.f};
  const unsigned short* ar = &As[(wm * 16 + lr) * 512 + lk * 8];
  const unsigned short* br = &Ws[(wn * 16 + lr) * 512 + lk * 8];
#pragma unroll
  for (int k0 = 0; k0 < 512; k0 += 64) {
    a0 = __builtin_amdgcn_mfma_f32_16x16x32_bf16(
        *(const short8*)(ar + k0), *(const short8*)(br + k0), a0, 0, 0, 0);
    a1 = __builtin_amdgcn_mfma_f32_16x16x32_bf16(
        *(const short8*)(ar + k0 + 32), *(const short8*)(br + k0 + 32), a1, 0,
        0, 0);
  }
  floatx4 acc = a0 + a1;
  int n = n0 + wn * 16 + lr;
  float bn = bias[n];
  // C/D layout (m89-verified): col = lane&15, row = (lane>>4)*4 + reg
#pragma unroll
  for (int r = 0; r < 4; r++) {
    int m = m0 + wm * 16 + lk * 4 + r;
    C[(size_t)m * 512 + n] = f2bf(elu1(acc[r] + bn));
  }
}

// ---- gate logits + softmax for one sample row b (one full wave) ------------
static __device__ __forceinline__ void gate_body(const unsigned short* G1,
                                                 const float* gw2,
                                                 const float* gb2, float* gates,
                                                 int b, int lane) {
  float xv[8];
#pragma unroll
  for (int t = 0; t < 8; t++) xv[t] = bf2f(G1[(size_t)b * 512 + t * 64 + lane]);
  float le[8];
#pragma unroll
  for (int e = 0; e < 8; e++) {
    float s = 0.f;
#pragma unroll
    for (int t = 0; t < 8; t++)
      s += xv[t] * gw2[(size_t)e * 512 + t * 64 + lane];
#pragma unroll
    for (int o = 32; o > 0; o >>= 1) s += __shfl_xor(s, o);
    le[e] = s + gb2[e];
  }
  float m = le[0];
#pragma unroll
  for (int e = 1; e < 8; e++) m = fmaxf(m, le[e]);
  float s = 0.f;
#pragma unroll
  for (int e = 0; e < 8; e++) {
    le[e] = __expf(le[e] - m);
    s += le[e];
  }
  float inv = 1.f / s;
  if (lane == 0) {
#pragma unroll
    for (int e = 0; e < 8; e++) gates[(size_t)b * 8 + e] = le[e] * inv;
  }
}

// ---- expert layer tile with in-register gate combine -----------------------
// out[m0:32, n0:32] = (Σ_e g[m,e]·(A @ alpha_e^T))[m,n] + Σ_e g[m,e]·beta_e[n]
template <int ACT>
static __device__ __forceinline__ void expert_stage(
    const unsigned short* Act, const float* alpha, const float* beta,
    const float* gates, unsigned short* Ob, float* Of, unsigned short* As,
    unsigned short* Ws, int tid, int m0, int n0, int wm, int wn, int lr,
    int lk) {
  stage_panel(Act, As, m0, tid);  // activations staged once for all 8 experts
  float g8[4][8];
#pragma unroll
  for (int r = 0; r < 4; r++) {
    int m = m0 + wm * 16 + lk * 4 + r;
    float4 ga = *(const float4*)&gates[(size_t)m * 8];
    float4 gb = *(const float4*)&gates[(size_t)m * 8 + 4];
    g8[r][0] = ga.x; g8[r][1] = ga.y; g8[r][2] = ga.z; g8[r][3] = ga.w;
    g8[r][4] = gb.x; g8[r][5] = gb.y; g8[r][6] = gb.z; g8[r][7] = gb.w;
  }
  __syncthreads();
  floatx4 fin = {0.f, 0.f, 0.f, 0.f};
#pragma unroll
  for (int e = 0; e < 8; e++) {
    if (e) __syncthreads();  // prior MFMA reads of Ws done before restage
    // stage W panel for expert e with inline fp32->bf16 conversion
    const float* Wsrc = alpha + ((size_t)e * 512 + n0) * 512;
#pragma unroll
    for (int i = 0; i < 8; i++) {
      int c = tid + i * 256;
      int r = c >> 6, k8 = (c & 63) * 8;
      float4 v0 = *(const float4*)&Wsrc[(size_t)r * 512 + k8];
      float4 v1 = *(const float4*)&Wsrc[(size_t)r * 512 + k8 + 4];
      short8 o;
      o[0] = (short)f2bf(v0.x); o[1] = (short)f2bf(v0.y);
      o[2] = (short)f2bf(v0.z); o[3] = (short)f2bf(v0.w);
      o[4] = (short)f2bf(v1.x); o[5] = (short)f2bf(v1.y);
      o[6] = (short)f2bf(v1.z); o[7] = (short)f2bf(v1.w);
      *(short8*)&Ws[c * 8] = o;
    }
    __syncthreads();
    floatx4 a0 = {0.f, 0.f, 0.f, 0.f}, a1 = {0.f, 0.f, 0.f, 0.f};
    const unsigned short* ar = &As[(wm * 16 + lr) * 512 + lk * 8];
    const unsigned short* br = &Ws[(wn * 16 + lr) * 512 + lk * 8];
#pragma unroll
    for (int k0 = 0; k0 < 512; k0 += 64) {
      a0 = __builtin_amdgcn_mfma_f32_16x16x32_bf16(
          *(const short8*)(ar + k0), *(const short8*)(br + k0), a0, 0, 0, 0);
      a1 = __builtin_amdgcn_mfma_f32_16x16x32_bf16(
          *(const short8*)(ar + k0 + 32), *(const short8*)(br + k0 + 32), a1, 0,
          0, 0);
    }
    floatx4 ae = a0 + a1;
#pragma unroll
    for (int r = 0; r < 4; r++) fin[r] += g8[r][e] * ae[r];
  }
  int n = n0 + wn * 16 + lr;
  float bv[8];
#pragma unroll
  for (int e = 0; e < 8; e++) bv[e] = beta[e * 512 + n];
#pragma unroll
  for (int r = 0; r < 4; r++) {
    float bs = 0.f;
#pragma unroll
    for (int e = 0; e < 8; e++) bs += g8[r][e] * bv[e];
    float v = fin[r] + bs;
    int m = m0 + wm * 16 + lk * 4 + r;
    if (ACT)
      Ob[(size_t)m * 512 + n] = f2bf(elu1(v));
    else
      Of[(size_t)m * 512 + n] = v;
  }
}

// ----------------------------- the mega-kernel ------------------------------
__global__ __launch_bounds__(256) void moe_mega(Params pr) {
  __shared__ unsigned short As[32 * 512];  // 32 KB
  __shared__ unsigned short Ws[32 * 512];  // 32 KB
  cg::grid_group grid = cg::this_grid();
  const int tid = threadIdx.x, blk = blockIdx.x;
  const int wave = tid >> 6, lane = tid & 63;
  const int wm = wave >> 1, wn = wave & 1;
  const int lr = lane & 15, lk = lane >> 4;
  const int m0 = (blk >> 4) * 32, n0 = (blk & 15) * 32;

  cvt_body(pr, blk, tid);
  grid.sync();
  gating_stage(pr.xb, pr.gw0b, pr.gb0, pr.G0, As, Ws, tid, m0, n0, wm, wn, lr, lk);
  grid.sync();
  gating_stage(pr.G0, pr.gw1b, pr.gb1, pr.G1, As, Ws, tid, m0, n0, wm, wn, lr, lk);
  grid.sync();
  if (blk < 128) gate_body(pr.G1, pr.gw2, pr.gb2, pr.gates, blk * 4 + wave, lane);
  grid.sync();
  expert_stage<1>(pr.xb, pr.a0, pr.b0, pr.gates, pr.H1, nullptr, As, Ws, tid,
                  m0, n0, wm, wn, lr, lk);
  grid.sync();
  expert_stage<1>(pr.H1, pr.a1, pr.b1, pr.gates, pr.H2, nullptr, As, Ws, tid,
                  m0, n0, wm, wn, lr, lk);
  grid.sync();
  expert_stage<0>(pr.H2, pr.a2, pr.b2, pr.gates, nullptr, pr.out, As, Ws, tid,
                  m0, n0, wm, wn, lr, lk);
}

// ------------------- fallback wrappers (non-cooperative) --------------------
__global__ __launch_bounds__(256) void k_cvt(Params pr) {
  cvt_body(pr, blockIdx.x, threadIdx.x);
}
__global__ __launch_bounds__(256) void k_gating(const unsigned short* A,
                                                const unsigned short* W,
                                                const float* bias,
                                                unsigned short* C) {
  __shared__ unsigned short As[32 * 512];
  __shared__ unsigned short Ws[32 * 512];
  const int tid = threadIdx.x, blk = blockIdx.x;
  const int wave = tid >> 6, lane = tid & 63;
  gating_stage(A, W, bias, C, As, Ws, tid, (blk >> 4) * 32, (blk & 15) * 32,
               wave >> 1, wave & 1, lane & 15, lane >> 4);
}
__global__ __launch_bounds__(64) void k_gate(const unsigned short* G1,
                                             const float* gw2,
                                             const float* gb2, float* gates) {
  gate_body(G1, gw2, gb2, gates, blockIdx.x, threadIdx.x);
}
template <int ACT>
__global__ __launch_bounds__(256) void k_expert(const unsigned short* Act,
                                                const float* alpha,
                                                const float* beta,
                                                const float* gates,
                                                unsigned short* Ob, float* Of) {
  __shared__ unsigned short As[32 * 512];
  __shared__ unsigned short Ws[32 * 512];
  const int tid = threadIdx.x, blk = blockIdx.x;
  const int wave = tid >> 6, lane = tid & 63;
  expert_stage<ACT>(Act, alpha, beta, gates, Ob, Of, As, Ws, tid,
                    (blk >> 4) * 32, (blk & 15) * 32, wave >> 1, wave & 1,
                    lane & 15, lane >> 4);
}

extern "C" void kernel_launch(void* const* d_in, const int* in_sizes, int n_in,
                              void* d_out, int out_size, void* d_ws,
                              size_t ws_size, hipStream_t stream) {
  char* ws = (char*)d_ws;
  auto alloc = [&](size_t bytes) {
    char* p = ws;
    ws += (bytes + 255) & ~(size_t)255;
    return p;
  };
  Params pr;
  pr.x = (const float*)d_in[0];
  pr.gw0 = (const float*)d_in[1];
  pr.gb0 = (const float*)d_in[2];
  pr.gw1 = (const float*)d_in[3];
  pr.gb1 = (const float*)d_in[4];
  pr.gw2 = (const float*)d_in[5];
  pr.gb2 = (const float*)d_in[6];
  pr.a0 = (const float*)d_in[7];
  pr.b0 = (const float*)d_in[8];
  pr.a1 = (const float*)d_in[9];
  pr.b1 = (const float*)d_in[10];
  pr.a2 = (const float*)d_in[11];
  pr.b2 = (const float*)d_in[12];
  pr.out = (float*)d_out;
  pr.xb = (unsigned short*)alloc(512 * 512 * 2);
  pr.gw0b = (unsigned short*)alloc(512 * 512 * 2);
  pr.gw1b = (unsigned short*)alloc(512 * 512 * 2);
  pr.G0 = (unsigned short*)alloc(512 * 512 * 2);
  pr.G1 = (unsigned short*)alloc(512 * 512 * 2);
  pr.H1 = (unsigned short*)alloc(512 * 512 * 2);
  pr.H2 = (unsigned short*)alloc(512 * 512 * 2);
  pr.gates = (float*)alloc(512 * 8 * 4);

  void* args[] = {&pr};
  hipError_t err = hipLaunchCooperativeKernel((const void*)moe_mega,
                                              dim3(NBLK), dim3(256), args, 0,
                                              stream);
  if (err != hipSuccess) {
    // deterministic fallback: same stages as separate launches
    k_cvt<<<256, 256, 0, stream>>>(pr);
    k_gating<<<256, 256, 0, stream>>>(pr.xb, pr.gw0b, pr.gb0, pr.G0);
    k_gating<<<256, 256, 0, stream>>>(pr.G0, pr.gw1b, pr.gb1, pr.G1);
    k_gate<<<512, 64, 0, stream>>>(pr.G1, pr.gw2, pr.gb2, pr.gates);
    k_expert<1><<<256, 256, 0, stream>>>(pr.xb, pr.a0, pr.b0, pr.gates, pr.H1,
                                         nullptr);
    k_expert<1><<<256, 256, 0, stream>>>(pr.H1, pr.a1, pr.b1, pr.gates, pr.H2,
                                         nullptr);
    k_expert<0><<<256, 256, 0, stream>>>(pr.H2, pr.a2, pr.b2, pr.gates,
                                         nullptr, pr.out);
  }
}

// Round 5
// 149.469 us; speedup vs baseline: 2.4946x; 2.4946x over previous
//
#include <hip/hip_runtime.h>
#include <hip/hip_bf16.h>
#include <math.h>

// Problem constants (B,F,H,E,O) = (512,512,512,8,512)
enum { Bq = 512, Fq = 512, Hq = 512, Eq = 8, Oq = 512 };

typedef __attribute__((ext_vector_type(8))) short short8;
typedef __attribute__((ext_vector_type(4))) float floatx4;

static __device__ __forceinline__ unsigned short f2bf(float f) {
  unsigned u = __float_as_uint(f);
  u += 0x7fffu + ((u >> 16) & 1u);
  return (unsigned short)(u >> 16);
}
static __device__ __forceinline__ float bf2f(unsigned short h) {
  return __uint_as_float(((unsigned)h) << 16);
}
static __device__ __forceinline__ float elu1(float v) {
  return v > 0.f ? v : (__expf(v) - 1.f);
}

// async global->LDS 16B copy (wave-uniform LDS base + lane*16 scatter)
typedef __attribute__((address_space(1))) const unsigned int gu32;
typedef __attribute__((address_space(3))) unsigned int lu32;
static __device__ __forceinline__ void gld16(const unsigned short* g,
                                             unsigned short* l) {
  __builtin_amdgcn_global_load_lds((gu32*)g, (lu32*)l, 16, 0, 0);
}

// XOR swizzle on 16B chunks: chunk q of row r lives at LDS chunk (q^ (r&7))'s
// slot (low 3 bits xored). Staging permutes the GLOBAL source (LDS side must
// stay lane-linear for global_load_lds); readers xor the chunk index.
static __device__ __forceinline__ int swz(int q, int r) {
  return (q & ~7) | ((q ^ r) & 7);
}

// ---------- fp32 -> bf16 convert, 3 big (alpha) + 3 small segments ----------
__global__ __launch_bounds__(256) void cvt6_kernel(
    const float* __restrict__ b0, const float* __restrict__ b1,
    const float* __restrict__ b2, unsigned short* __restrict__ db0,
    unsigned short* __restrict__ db1, unsigned short* __restrict__ db2,
    const float* __restrict__ s0, const float* __restrict__ s1,
    const float* __restrict__ s2, unsigned short* __restrict__ ds0,
    unsigned short* __restrict__ ds1, unsigned short* __restrict__ ds2,
    int nb, int ns) {
  int i = blockIdx.x * 256 + threadIdx.x;
  const float4* s;
  unsigned short* d;
  int j;
  if (i < 3 * nb) {
    int seg = i / nb;
    j = i - seg * nb;
    s = (seg == 0) ? (const float4*)b0
      : (seg == 1) ? (const float4*)b1 : (const float4*)b2;
    d = (seg == 0) ? db0 : (seg == 1) ? db1 : db2;
  } else {
    int k = i - 3 * nb;
    if (k >= 3 * ns) return;
    int seg = k / ns;
    j = k - seg * ns;
    s = (seg == 0) ? (const float4*)s0
      : (seg == 1) ? (const float4*)s1 : (const float4*)s2;
    d = (seg == 0) ? ds0 : (seg == 1) ? ds1 : ds2;
  }
  float4 v = s[j];
  ushort4 o;
  o.x = f2bf(v.x); o.y = f2bf(v.y); o.z = f2bf(v.z); o.w = f2bf(v.w);
  *(ushort4*)(d + 4 * (size_t)j) = o;
}

// ------- gating GEMM: 32x32 tile, BK=512 (full K), ONE barrier/block --------
// C[m0:32, n0:32] = elu(A @ W^T + bias); grid (16,16), 64 KB LDS, 2 blk/CU.
__global__ __launch_bounds__(256) void gating_gemm(
    const unsigned short* __restrict__ A, const unsigned short* __restrict__ W,
    const float* __restrict__ bias, unsigned short* __restrict__ C) {
  __shared__ unsigned short As[32 * 512];
  __shared__ unsigned short Ws[32 * 512];
  const int tid = threadIdx.x;
  const int wave = tid >> 6, lane = tid & 63;
  const int wm = wave >> 1, wn = wave & 1;
  const int lr = lane & 15, lk = lane >> 4;
  const int m0 = blockIdx.y * 32, n0 = blockIdx.x * 32;
  // stage 32x512 panels: 64 chunks/row, 2048 chunks each, 8 per thread
#pragma unroll
  for (int i = 0; i < 8; i++) {
    int c = tid + i * 256;
    int r = c >> 6, ql = c & 63;
    int qg = swz(ql, r);
    gld16(&A[(size_t)(m0 + r) * 512 + qg * 8], &As[(c & ~63) * 8]);
  }
#pragma unroll
  for (int i = 0; i < 8; i++) {
    int c = tid + i * 256;
    int r = c >> 6, ql = c & 63;
    int qg = swz(ql, r);
    gld16(&W[(size_t)(n0 + r) * 512 + qg * 8], &Ws[(c & ~63) * 8]);
  }
  __syncthreads();
  const int rA = wm * 16 + lr, rB = wn * 16 + lr;
  floatx4 ac[4];
#pragma unroll
  for (int j = 0; j < 4; j++) ac[j] = (floatx4){0.f, 0.f, 0.f, 0.f};
  // 16 MFMAs as 4 independent chains of 4 (ILP for latency hiding)
#pragma unroll
  for (int t = 0; t < 4; t++) {
#pragma unroll
    for (int j = 0; j < 4; j++) {
      int q = ((j * 128 + t * 32) >> 3) + lk;
      short8 av = *(const short8*)&As[rA * 512 + swz(q, rA) * 8];
      short8 bv = *(const short8*)&Ws[rB * 512 + swz(q, rB) * 8];
      ac[j] = __builtin_amdgcn_mfma_f32_16x16x32_bf16(av, bv, ac[j], 0, 0, 0);
    }
  }
  floatx4 acc = (ac[0] + ac[1]) + (ac[2] + ac[3]);
  int n = n0 + wn * 16 + lr;
  float bn = bias[n];
  // C/D layout (m89-verified): col = lane&15, row = (lane>>4)*4 + reg
#pragma unroll
  for (int r = 0; r < 4; r++) {
    int m = m0 + wm * 16 + lk * 4 + r;
    C[(size_t)m * 512 + n] = f2bf(elu1(acc[r] + bn));
  }
}

// ---- expert GEMM: 64x64 tile, BK=256 (split-K half), ONE barrier/block -----
// P[ks*8+e][m][nloc] = g[m,e] * (A[m,:] @ alpha_e[n,:]) partial over K-half.
// grid (64, 8, 2): x = global n-tile (e = x>>3), y = m-tile, z = K-half.
__global__ __launch_bounds__(256) void expert_gemm(
    const unsigned short* __restrict__ A,   // [512,512] bf16 activations
    const unsigned short* __restrict__ Wb,  // [4096,512] bf16 alpha bank
    const float* __restrict__ g,            // [512,8] gates
    float* __restrict__ P) {                // [16][512][512] partials
  __shared__ unsigned short As[64 * 256];
  __shared__ unsigned short Ws[64 * 256];
  const int tid = threadIdx.x;
  const int wave = tid >> 6, lane = tid & 63;
  const int wm = wave >> 1, wn = wave & 1;
  const int lr = lane & 15, lk = lane >> 4;
  const int nt = blockIdx.x;         // global 64-col tile in [0,64)
  const int m0 = blockIdx.y * 64;
  const int ks = blockIdx.z;
  const int e = nt >> 3;
  const int n0g = nt * 64;           // row in alpha bank
  const int n0l = (nt & 7) * 64;     // col within expert output
  const int kbeg = ks * 256;
  // stage 64x256 panels: 32 chunks/row, 2048 chunks each, 8 per thread
#pragma unroll
  for (int i = 0; i < 8; i++) {
    int c = tid + i * 256;
    int r = c >> 5, ql = c & 31;
    int qg = swz(ql, r);
    gld16(&A[(size_t)(m0 + r) * 512 + kbeg + qg * 8], &As[(c & ~63) * 8]);
  }
#pragma unroll
  for (int i = 0; i < 8; i++) {
    int c = tid + i * 256;
    int r = c >> 5, ql = c & 31;
    int qg = swz(ql, r);
    gld16(&Wb[(size_t)(n0g + r) * 512 + kbeg + qg * 8], &Ws[(c & ~63) * 8]);
  }
  __syncthreads();
  floatx4 acc[2][2];
#pragma unroll
  for (int i = 0; i < 2; i++)
#pragma unroll
    for (int j = 0; j < 2; j++) acc[i][j] = (floatx4){0.f, 0.f, 0.f, 0.f};
  const int rA0 = wm * 32 + lr, rB0 = wn * 32 + lr;
#pragma unroll
  for (int kk = 0; kk < 256; kk += 32) {
    int q = (kk >> 3) + lk;
    short8 af[2], bf[2];
#pragma unroll
    for (int i = 0; i < 2; i++) {
      int r = rA0 + i * 16;
      af[i] = *(const short8*)&As[r * 256 + swz(q, r) * 8];
    }
#pragma unroll
    for (int j = 0; j < 2; j++) {
      int r = rB0 + j * 16;
      bf[j] = *(const short8*)&Ws[r * 256 + swz(q, r) * 8];
    }
#pragma unroll
    for (int i = 0; i < 2; i++)
#pragma unroll
      for (int j = 0; j < 2; j++)
        acc[i][j] = __builtin_amdgcn_mfma_f32_16x16x32_bf16(af[i], bf[j],
                                                            acc[i][j], 0, 0, 0);
  }
  float* Po = P + (size_t)(ks * 8 + e) * Bq * Hq;
#pragma unroll
  for (int i = 0; i < 2; i++) {
#pragma unroll
    for (int j = 0; j < 2; j++) {
#pragma unroll
      for (int r = 0; r < 4; r++) {
        int m = m0 + wm * 32 + i * 16 + lk * 4 + r;
        int n = n0l + wn * 32 + j * 16 + lr;
        Po[(size_t)m * 512 + n] = acc[i][j][r] * g[m * Eq + e];
      }
    }
  }
}

// ---------------- gate logits + softmax (one wave per sample) ----------------
__global__ __launch_bounds__(64) void gate_kernel(
    const unsigned short* __restrict__ G1,  // [B,H] bf16
    const float* __restrict__ gw2,          // [E,H]
    const float* __restrict__ gb2,          // [E]
    float* __restrict__ g) {                // [B,E]
  int b = blockIdx.x;
  int lane = threadIdx.x;
  float xv[8];
#pragma unroll
  for (int t = 0; t < 8; t++) xv[t] = bf2f(G1[(size_t)b * Hq + t * 64 + lane]);
  float le[Eq];
#pragma unroll
  for (int e = 0; e < Eq; e++) {
    float p = 0.f;
#pragma unroll
    for (int t = 0; t < 8; t++)
      p += xv[t] * gw2[(size_t)e * Hq + t * 64 + lane];
#pragma unroll
    for (int o = 32; o > 0; o >>= 1) p += __shfl_xor(p, o);
    le[e] = p + gb2[e];
  }
  float m = le[0];
#pragma unroll
  for (int e = 1; e < Eq; e++) m = fmaxf(m, le[e]);
  float s = 0.f;
#pragma unroll
  for (int e = 0; e < Eq; e++) {
    le[e] = __expf(le[e] - m);
    s += le[e];
  }
  float inv = 1.f / s;
  if (lane == 0) {
#pragma unroll
    for (int e = 0; e < Eq; e++) g[(size_t)b * Eq + e] = le[e] * inv;
  }
}

// ----- slice reduce: out = sum_z P[z] + sum_e g[b,e]*beta_e  (+opt ELU) -----
template <int ACT>
__global__ __launch_bounds__(256) void reduce_kernel(
    const float* __restrict__ P,     // [16][B][H]
    const float* __restrict__ g,     // [B, E]
    const float* __restrict__ beta,  // [E*H]
    unsigned short* __restrict__ outb, float* __restrict__ outf) {
  int idx = blockIdx.x * 256 + threadIdx.x;  // over B*H/4
  int b = idx >> 7, h4 = (idx & 127) << 2;
  float4 s = {0.f, 0.f, 0.f, 0.f};
#pragma unroll
  for (int z = 0; z < 16; z++) {
    float4 v = *(const float4*)&P[((size_t)z * Bq + b) * Hq + h4];
    s.x += v.x; s.y += v.y; s.z += v.z; s.w += v.w;
  }
  const float* gb = g + (size_t)b * Eq;
#pragma unroll
  for (int e = 0; e < Eq; e++) {
    float ge = gb[e];
    float4 bv = *(const float4*)&beta[e * Hq + h4];
    s.x += ge * bv.x; s.y += ge * bv.y; s.z += ge * bv.z; s.w += ge * bv.w;
  }
  if (ACT) {
    ushort4 o;
    o.x = f2bf(elu1(s.x)); o.y = f2bf(elu1(s.y));
    o.z = f2bf(elu1(s.z)); o.w = f2bf(elu1(s.w));
    *(ushort4*)&outb[(size_t)idx * 4] = o;
  } else {
    *(float4*)&outf[(size_t)idx * 4] = s;
  }
}

extern "C" void kernel_launch(void* const* d_in, const int* in_sizes, int n_in,
                              void* d_out, int out_size, void* d_ws,
                              size_t ws_size, hipStream_t stream) {
  const float* x = (const float*)d_in[0];
  const float* gw0 = (const float*)d_in[1];
  const float* gb0 = (const float*)d_in[2];
  const float* gw1 = (const float*)d_in[3];
  const float* gb1 = (const float*)d_in[4];
  const float* gw2 = (const float*)d_in[5];
  const float* gb2 = (const float*)d_in[6];
  const float* alpha0 = (const float*)d_in[7];
  const float* beta0 = (const float*)d_in[8];
  const float* alpha1 = (const float*)d_in[9];
  const float* beta1 = (const float*)d_in[10];
  const float* alpha2 = (const float*)d_in[11];
  const float* beta2 = (const float*)d_in[12];
  float* out = (float*)d_out;

  char* ws = (char*)d_ws;
  auto alloc = [&](size_t bytes) {
    char* p = ws;
    ws += (bytes + 255) & ~(size_t)255;
    return p;
  };
  unsigned short* xb = (unsigned short*)alloc((size_t)Bq * Fq * 2);
  unsigned short* gw0b = (unsigned short*)alloc((size_t)Hq * Fq * 2);
  unsigned short* gw1b = (unsigned short*)alloc((size_t)Hq * Hq * 2);
  unsigned short* a0b = (unsigned short*)alloc((size_t)Eq * Hq * Fq * 2);
  unsigned short* a1b = (unsigned short*)alloc((size_t)Eq * Hq * Hq * 2);
  unsigned short* a2b = (unsigned short*)alloc((size_t)Eq * Oq * Hq * 2);
  unsigned short* G0b = (unsigned short*)alloc((size_t)Bq * Hq * 2);
  unsigned short* G1b = (unsigned short*)alloc((size_t)Bq * Hq * 2);
  unsigned short* H1b = (unsigned short*)alloc((size_t)Bq * Hq * 2);
  unsigned short* H2b = (unsigned short*)alloc((size_t)Bq * Hq * 2);
  float* gates = (float*)alloc((size_t)Bq * Eq * 4);
  float* P = (float*)alloc((size_t)16 * Bq * Hq * 4);

  // 1) all fp32->bf16 converts in one launch
  {
    int nb = (Eq * Hq * Fq) / 4, ns = (Bq * Fq) / 4;
    int total = 3 * nb + 3 * ns;
    cvt6_kernel<<<(total + 255) / 256, 256, 0, stream>>>(
        alpha0, alpha1, alpha2, a0b, a1b, a2b, x, gw0, gw1, xb, gw0b, gw1b,
        nb, ns);
  }

  // 2) gating MLP: single-barrier 32x32 tiles, 256 blocks each
  dim3 gg(16, 16);
  gating_gemm<<<gg, 256, 0, stream>>>(xb, gw0b, gb0, G0b);
  gating_gemm<<<gg, 256, 0, stream>>>(G0b, gw1b, gb1, G1b);

  // 3) gate logits + softmax
  gate_kernel<<<Bq, 64, 0, stream>>>(G1b, gw2, gb2, gates);

  // 4) experts: single-barrier 64x64x256 blocks (1024 each) + slice reduce
  dim3 ge(64, 8, 2);
  dim3 gr((Bq * Hq / 4) / 256);
  expert_gemm<<<ge, 256, 0, stream>>>(xb, a0b, gates, P);
  reduce_kernel<1><<<gr, 256, 0, stream>>>(P, gates, beta0, H1b, nullptr);
  expert_gemm<<<ge, 256, 0, stream>>>(H1b, a1b, gates, P);
  reduce_kernel<1><<<gr, 256, 0, stream>>>(P, gates, beta1, H2b, nullptr);
  expert_gemm<<<ge, 256, 0, stream>>>(H2b, a2b, gates, P);
  reduce_kernel<0><<<gr, 256, 0, stream>>>(P, gates, beta2, nullptr, out);
}

// Round 6
// 139.656 us; speedup vs baseline: 2.6699x; 1.0703x over previous
//
#include <hip/hip_runtime.h>
#include <hip/hip_bf16.h>
#include <math.h>

// Problem constants (B,F,H,E,O) = (512,512,512,8,512)
enum { Bq = 512, Fq = 512, Hq = 512, Eq = 8, Oq = 512 };

typedef __attribute__((ext_vector_type(8))) short short8;
typedef __attribute__((ext_vector_type(4))) float floatx4;

static __device__ __forceinline__ unsigned short f2bf(float f) {
  unsigned u = __float_as_uint(f);
  u += 0x7fffu + ((u >> 16) & 1u);
  return (unsigned short)(u >> 16);
}
static __device__ __forceinline__ float bf2f(unsigned short h) {
  return __uint_as_float(((unsigned)h) << 16);
}
static __device__ __forceinline__ float elu1(float v) {
  return v > 0.f ? v : (__expf(v) - 1.f);
}

// async global->LDS 16B copy (wave-uniform LDS base + lane*16 scatter)
typedef __attribute__((address_space(1))) const unsigned int gu32;
typedef __attribute__((address_space(3))) unsigned int lu32;
static __device__ __forceinline__ void gld16(const unsigned short* g,
                                             unsigned short* l) {
  __builtin_amdgcn_global_load_lds((gu32*)g, (lu32*)l, 16, 0, 0);
}

// XOR swizzle on 16B chunks (breaks the 16-way fragment-read bank conflict
// down to 2-way == free per m136). Staging permutes the GLOBAL source so the
// LDS side stays lane-linear for global_load_lds; readers xor the chunk idx.
static __device__ __forceinline__ int swz(int q, int r) {
  return (q & ~7) | ((q ^ r) & 7);
}

// ---------- fp32 -> bf16 convert, 3 big (alpha) + 3 small segments ----------
__global__ __launch_bounds__(256) void cvt6_kernel(
    const float* __restrict__ b0, const float* __restrict__ b1,
    const float* __restrict__ b2, unsigned short* __restrict__ db0,
    unsigned short* __restrict__ db1, unsigned short* __restrict__ db2,
    const float* __restrict__ s0, const float* __restrict__ s1,
    const float* __restrict__ s2, unsigned short* __restrict__ ds0,
    unsigned short* __restrict__ ds1, unsigned short* __restrict__ ds2,
    int nb, int ns) {
  int i = blockIdx.x * 256 + threadIdx.x;
  const float4* s;
  unsigned short* d;
  int j;
  if (i < 3 * nb) {
    int seg = i / nb;
    j = i - seg * nb;
    s = (seg == 0) ? (const float4*)b0
      : (seg == 1) ? (const float4*)b1 : (const float4*)b2;
    d = (seg == 0) ? db0 : (seg == 1) ? db1 : db2;
  } else {
    int k = i - 3 * nb;
    if (k >= 3 * ns) return;
    int seg = k / ns;
    j = k - seg * ns;
    s = (seg == 0) ? (const float4*)s0
      : (seg == 1) ? (const float4*)s1 : (const float4*)s2;
    d = (seg == 0) ? ds0 : (seg == 1) ? ds1 : ds2;
  }
  float4 v = s[j];
  ushort4 o;
  o.x = f2bf(v.x); o.y = f2bf(v.y); o.z = f2bf(v.z); o.w = f2bf(v.w);
  *(ushort4*)(d + 4 * (size_t)j) = o;
}

// ------- gating GEMM: 32x32 tile, BK=512 (full K), ONE barrier/block --------
__global__ __launch_bounds__(256) void gating_gemm(
    const unsigned short* __restrict__ A, const unsigned short* __restrict__ W,
    const float* __restrict__ bias, unsigned short* __restrict__ C) {
  __shared__ unsigned short As[32 * 512];
  __shared__ unsigned short Ws[32 * 512];
  const int tid = threadIdx.x;
  const int wave = tid >> 6, lane = tid & 63;
  const int wm = wave >> 1, wn = wave & 1;
  const int lr = lane & 15, lk = lane >> 4;
  const int m0 = blockIdx.y * 32, n0 = blockIdx.x * 32;
#pragma unroll
  for (int i = 0; i < 8; i++) {
    int c = tid + i * 256;
    int r = c >> 6, ql = c & 63;
    gld16(&A[(size_t)(m0 + r) * 512 + swz(ql, r) * 8], &As[(c & ~63) * 8]);
  }
#pragma unroll
  for (int i = 0; i < 8; i++) {
    int c = tid + i * 256;
    int r = c >> 6, ql = c & 63;
    gld16(&W[(size_t)(n0 + r) * 512 + swz(ql, r) * 8], &Ws[(c & ~63) * 8]);
  }
  __syncthreads();
  const int rA = wm * 16 + lr, rB = wn * 16 + lr;
  floatx4 ac[4];
#pragma unroll
  for (int j = 0; j < 4; j++) ac[j] = (floatx4){0.f, 0.f, 0.f, 0.f};
#pragma unroll
  for (int t = 0; t < 4; t++) {
#pragma unroll
    for (int j = 0; j < 4; j++) {
      int q = ((j * 128 + t * 32) >> 3) + lk;
      short8 av = *(const short8*)&As[rA * 512 + swz(q, rA) * 8];
      short8 bv = *(const short8*)&Ws[rB * 512 + swz(q, rB) * 8];
      ac[j] = __builtin_amdgcn_mfma_f32_16x16x32_bf16(av, bv, ac[j], 0, 0, 0);
    }
  }
  floatx4 acc = (ac[0] + ac[1]) + (ac[2] + ac[3]);
  int n = n0 + wn * 16 + lr;
  float bn = bias[n];
  // C/D layout (m89-verified): col = lane&15, row = (lane>>4)*4 + reg
#pragma unroll
  for (int r = 0; r < 4; r++) {
    int m = m0 + wm * 16 + lk * 4 + r;
    C[(size_t)m * 512 + n] = f2bf(elu1(acc[r] + bn));
  }
}

// ---- expert GEMM, all 8 experts per block, in-register gate combine --------
// grid (16 n-tiles, 16 m-tiles, 2 k-halves), 48 KB LDS -> 3 blocks/CU.
// P[kz][m][n] = sum_e g[m,e] * (A[m, kz*256:+256] @ alpha_e[n, same]^T)
// Double-buffered W panels: one barrier per expert, prefetch overlaps MFMA.
__global__ __launch_bounds__(256) void expert_gemm(
    const unsigned short* __restrict__ A,   // [512,512] bf16 activations
    const unsigned short* __restrict__ Wb,  // [E*512,512] bf16 alpha bank
    const float* __restrict__ g,            // [512,8] gates
    float* __restrict__ P) {                // [2][512][512] fp32 partials
  __shared__ unsigned short As[32 * 256];      // 16 KB
  __shared__ unsigned short Ws[2][32 * 256];   // 2 x 16 KB
  const int tid = threadIdx.x;
  const int wave = tid >> 6, lane = tid & 63;
  const int wm = wave >> 1, wn = wave & 1;
  const int lr = lane & 15, lk = lane >> 4;
  const int m0 = blockIdx.y * 32, n0 = blockIdx.x * 32;
  const int kz = blockIdx.z, kbeg = kz * 256;

  // stage A panel (32x256): 1024 chunks, 4 per thread
#pragma unroll
  for (int i = 0; i < 4; i++) {
    int c = tid + i * 256;
    int r = c >> 5, ql = c & 31;
    gld16(&A[(size_t)(m0 + r) * 512 + kbeg + swz(ql, r) * 8],
          &As[(c & ~63) * 8]);
  }
  // stage W panel for expert 0 into buffer 0
#pragma unroll
  for (int i = 0; i < 4; i++) {
    int c = tid + i * 256;
    int r = c >> 5, ql = c & 31;
    gld16(&Wb[(size_t)(n0 + r) * 512 + kbeg + swz(ql, r) * 8],
          &Ws[0][(c & ~63) * 8]);
  }
  // gates for this lane's 4 output rows
  float g8[4][8];
#pragma unroll
  for (int r = 0; r < 4; r++) {
    int m = m0 + wm * 16 + lk * 4 + r;
    float4 ga = *(const float4*)&g[(size_t)m * 8];
    float4 gb = *(const float4*)&g[(size_t)m * 8 + 4];
    g8[r][0] = ga.x; g8[r][1] = ga.y; g8[r][2] = ga.z; g8[r][3] = ga.w;
    g8[r][4] = gb.x; g8[r][5] = gb.y; g8[r][6] = gb.z; g8[r][7] = gb.w;
  }

  const int rA = wm * 16 + lr, rB = wn * 16 + lr;
  floatx4 fin = {0.f, 0.f, 0.f, 0.f};
#pragma unroll
  for (int e = 0; e < 8; e++) {
    __syncthreads();  // drains A + W[e] staging; fences buffer reuse
    if (e < 7) {      // prefetch W[e+1]; overlaps with MFMA on W[e]
      const unsigned short* Wn = Wb + ((size_t)(e + 1) * 512 + n0) * 512 + kbeg;
#pragma unroll
      for (int i = 0; i < 4; i++) {
        int c = tid + i * 256;
        int r = c >> 5, ql = c & 31;
        gld16(&Wn[(size_t)r * 512 + swz(ql, r) * 8],
              &Ws[(e + 1) & 1][(c & ~63) * 8]);
      }
    }
    const unsigned short* wb = Ws[e & 1];
    floatx4 c0 = {0.f, 0.f, 0.f, 0.f}, c1 = {0.f, 0.f, 0.f, 0.f};
#pragma unroll
    for (int s = 0; s < 8; s++) {
      int q = s * 4 + lk;
      short8 av = *(const short8*)&As[rA * 256 + swz(q, rA) * 8];
      short8 bv = *(const short8*)&wb[rB * 256 + swz(q, rB) * 8];
      if (s & 1)
        c1 = __builtin_amdgcn_mfma_f32_16x16x32_bf16(av, bv, c1, 0, 0, 0);
      else
        c0 = __builtin_amdgcn_mfma_f32_16x16x32_bf16(av, bv, c0, 0, 0, 0);
    }
    floatx4 ae = c0 + c1;
#pragma unroll
    for (int r = 0; r < 4; r++) fin[r] += g8[r][e] * ae[r];
  }

  float* Po = P + (size_t)kz * Bq * Hq;
  int n = n0 + wn * 16 + lr;
#pragma unroll
  for (int r = 0; r < 4; r++) {
    int m = m0 + wm * 16 + lk * 4 + r;
    Po[(size_t)m * 512 + n] = fin[r];
  }
}

// ---------------- gate logits + softmax (one wave per sample) ----------------
__global__ __launch_bounds__(64) void gate_kernel(
    const unsigned short* __restrict__ G1,  // [B,H] bf16
    const float* __restrict__ gw2,          // [E,H]
    const float* __restrict__ gb2,          // [E]
    float* __restrict__ g) {                // [B,E]
  int b = blockIdx.x;
  int lane = threadIdx.x;
  float xv[8];
#pragma unroll
  for (int t = 0; t < 8; t++) xv[t] = bf2f(G1[(size_t)b * Hq + t * 64 + lane]);
  float le[Eq];
#pragma unroll
  for (int e = 0; e < Eq; e++) {
    float p = 0.f;
#pragma unroll
    for (int t = 0; t < 8; t++)
      p += xv[t] * gw2[(size_t)e * Hq + t * 64 + lane];
#pragma unroll
    for (int o = 32; o > 0; o >>= 1) p += __shfl_xor(p, o);
    le[e] = p + gb2[e];
  }
  float m = le[0];
#pragma unroll
  for (int e = 1; e < Eq; e++) m = fmaxf(m, le[e]);
  float s = 0.f;
#pragma unroll
  for (int e = 0; e < Eq; e++) {
    le[e] = __expf(le[e] - m);
    s += le[e];
  }
  float inv = 1.f / s;
  if (lane == 0) {
#pragma unroll
    for (int e = 0; e < Eq; e++) g[(size_t)b * Eq + e] = le[e] * inv;
  }
}

// ----- reduce: out = P[0]+P[1] + sum_e g[b,e]*beta_e  (+opt ELU/bf16) -------
template <int ACT>
__global__ __launch_bounds__(256) void reduce_kernel(
    const float* __restrict__ P,     // [2][B][H]
    const float* __restrict__ g,     // [B, E]
    const float* __restrict__ beta,  // [E*H]
    unsigned short* __restrict__ outb, float* __restrict__ outf) {
  int idx = blockIdx.x * 256 + threadIdx.x;  // over B*H/4
  int b = idx >> 7, h4 = (idx & 127) << 2;
  float4 v0 = *(const float4*)&P[((size_t)b) * Hq + h4];
  float4 v1 = *(const float4*)&P[((size_t)Bq + b) * Hq + h4];
  float4 s = {v0.x + v1.x, v0.y + v1.y, v0.z + v1.z, v0.w + v1.w};
  const float* gb = g + (size_t)b * Eq;
#pragma unroll
  for (int e = 0; e < Eq; e++) {
    float ge = gb[e];
    float4 bv = *(const float4*)&beta[e * Hq + h4];
    s.x += ge * bv.x; s.y += ge * bv.y; s.z += ge * bv.z; s.w += ge * bv.w;
  }
  if (ACT) {
    ushort4 o;
    o.x = f2bf(elu1(s.x)); o.y = f2bf(elu1(s.y));
    o.z = f2bf(elu1(s.z)); o.w = f2bf(elu1(s.w));
    *(ushort4*)&outb[(size_t)idx * 4] = o;
  } else {
    *(float4*)&outf[(size_t)idx * 4] = s;
  }
}

extern "C" void kernel_launch(void* const* d_in, const int* in_sizes, int n_in,
                              void* d_out, int out_size, void* d_ws,
                              size_t ws_size, hipStream_t stream) {
  const float* x = (const float*)d_in[0];
  const float* gw0 = (const float*)d_in[1];
  const float* gb0 = (const float*)d_in[2];
  const float* gw1 = (const float*)d_in[3];
  const float* gb1 = (const float*)d_in[4];
  const float* gw2 = (const float*)d_in[5];
  const float* gb2 = (const float*)d_in[6];
  const float* alpha0 = (const float*)d_in[7];
  const float* beta0 = (const float*)d_in[8];
  const float* alpha1 = (const float*)d_in[9];
  const float* beta1 = (const float*)d_in[10];
  const float* alpha2 = (const float*)d_in[11];
  const float* beta2 = (const float*)d_in[12];
  float* out = (float*)d_out;

  char* ws = (char*)d_ws;
  auto alloc = [&](size_t bytes) {
    char* p = ws;
    ws += (bytes + 255) & ~(size_t)255;
    return p;
  };
  unsigned short* xb = (unsigned short*)alloc((size_t)Bq * Fq * 2);
  unsigned short* gw0b = (unsigned short*)alloc((size_t)Hq * Fq * 2);
  unsigned short* gw1b = (unsigned short*)alloc((size_t)Hq * Hq * 2);
  unsigned short* a0b = (unsigned short*)alloc((size_t)Eq * Hq * Fq * 2);
  unsigned short* a1b = (unsigned short*)alloc((size_t)Eq * Hq * Hq * 2);
  unsigned short* a2b = (unsigned short*)alloc((size_t)Eq * Oq * Hq * 2);
  unsigned short* G0b = (unsigned short*)alloc((size_t)Bq * Hq * 2);
  unsigned short* G1b = (unsigned short*)alloc((size_t)Bq * Hq * 2);
  unsigned short* H1b = (unsigned short*)alloc((size_t)Bq * Hq * 2);
  unsigned short* H2b = (unsigned short*)alloc((size_t)Bq * Hq * 2);
  float* gates = (float*)alloc((size_t)Bq * Eq * 4);
  float* P = (float*)alloc((size_t)2 * Bq * Hq * 4);

  // 1) all fp32->bf16 converts in one launch
  {
    int nb = (Eq * Hq * Fq) / 4, ns = (Bq * Fq) / 4;
    int total = 3 * nb + 3 * ns;
    cvt6_kernel<<<(total + 255) / 256, 256, 0, stream>>>(
        alpha0, alpha1, alpha2, a0b, a1b, a2b, x, gw0, gw1, xb, gw0b, gw1b,
        nb, ns);
  }

  // 2) gating MLP: single-barrier 32x32 tiles, 256 blocks each
  dim3 gg(16, 16);
  gating_gemm<<<gg, 256, 0, stream>>>(xb, gw0b, gb0, G0b);
  gating_gemm<<<gg, 256, 0, stream>>>(G0b, gw1b, gb1, G1b);

  // 3) gate logits + softmax
  gate_kernel<<<Bq, 64, 0, stream>>>(G1b, gw2, gb2, gates);

  // 4) experts: all-8-expert blocks w/ dbuf W prefetch (512 blocks) + reduce
  dim3 ge(16, 16, 2);
  dim3 gr((Bq * Hq / 4) / 256);
  expert_gemm<<<ge, 256, 0, stream>>>(xb, a0b, gates, P);
  reduce_kernel<1><<<gr, 256, 0, stream>>>(P, gates, beta0, H1b, nullptr);
  expert_gemm<<<ge, 256, 0, stream>>>(H1b, a1b, gates, P);
  reduce_kernel<1><<<gr, 256, 0, stream>>>(P, gates, beta1, H2b, nullptr);
  expert_gemm<<<ge, 256, 0, stream>>>(H2b, a2b, gates, P);
  reduce_kernel<0><<<gr, 256, 0, stream>>>(P, gates, beta2, nullptr, out);
}

// Round 7
// 137.338 us; speedup vs baseline: 2.7149x; 1.0169x over previous
//
#include <hip/hip_runtime.h>
#include <hip/hip_bf16.h>
#include <math.h>

// Problem constants (B,F,H,E,O) = (512,512,512,8,512)
enum { Bq = 512, Fq = 512, Hq = 512, Eq = 8, Oq = 512 };

typedef __attribute__((ext_vector_type(8))) short short8;
typedef __attribute__((ext_vector_type(4))) float floatx4;

static __device__ __forceinline__ unsigned short f2bf(float f) {
  unsigned u = __float_as_uint(f);
  u += 0x7fffu + ((u >> 16) & 1u);
  return (unsigned short)(u >> 16);
}
static __device__ __forceinline__ float bf2f(unsigned short h) {
  return __uint_as_float(((unsigned)h) << 16);
}
static __device__ __forceinline__ float elu1(float v) {
  return v > 0.f ? v : (__expf(v) - 1.f);
}

// async global->LDS 16B copy (wave-uniform LDS base + lane*16 scatter)
typedef __attribute__((address_space(1))) const unsigned int gu32;
typedef __attribute__((address_space(3))) unsigned int lu32;
static __device__ __forceinline__ void gld16(const unsigned short* g,
                                             unsigned short* l) {
  __builtin_amdgcn_global_load_lds((gu32*)g, (lu32*)l, 16, 0, 0);
}

// XOR swizzle on 16B chunks (16-way fragment-read conflicts -> 2-way = free).
// gld16 staging permutes the GLOBAL source; VALU staging writes chunk q of
// row r to LDS slot swz(q,r); readers xor the chunk index identically.
static __device__ __forceinline__ int swz(int q, int r) {
  return (q & ~7) | ((q ^ r) & 7);
}

// ---------- fp32 -> bf16 convert, 3 big (alpha) + 3 small segments ----------
__global__ __launch_bounds__(256) void cvt6_kernel(
    const float* __restrict__ b0, const float* __restrict__ b1,
    const float* __restrict__ b2, unsigned short* __restrict__ db0,
    unsigned short* __restrict__ db1, unsigned short* __restrict__ db2,
    const float* __restrict__ s0, const float* __restrict__ s1,
    const float* __restrict__ s2, unsigned short* __restrict__ ds0,
    unsigned short* __restrict__ ds1, unsigned short* __restrict__ ds2,
    int nb, int ns) {
  int i = blockIdx.x * 256 + threadIdx.x;
  const float4* s;
  unsigned short* d;
  int j;
  if (i < 3 * nb) {
    int seg = i / nb;
    j = i - seg * nb;
    s = (seg == 0) ? (const float4*)b0
      : (seg == 1) ? (const float4*)b1 : (const float4*)b2;
    d = (seg == 0) ? db0 : (seg == 1) ? db1 : db2;
  } else {
    int k = i - 3 * nb;
    if (k >= 3 * ns) return;
    int seg = k / ns;
    j = k - seg * ns;
    s = (seg == 0) ? (const float4*)s0
      : (seg == 1) ? (const float4*)s1 : (const float4*)s2;
    d = (seg == 0) ? ds0 : (seg == 1) ? ds1 : ds2;
  }
  float4 v = s[j];
  ushort4 o;
  o.x = f2bf(v.x); o.y = f2bf(v.y); o.z = f2bf(v.z); o.w = f2bf(v.w);
  *(ushort4*)(d + 4 * (size_t)j) = o;
}

// ------- gating GEMM: 32x32 tile, BK=512 (full K), ONE barrier/block --------
__global__ __launch_bounds__(256) void gating_gemm(
    const unsigned short* __restrict__ A, const unsigned short* __restrict__ W,
    const float* __restrict__ bias, unsigned short* __restrict__ C) {
  __shared__ unsigned short As[32 * 512];
  __shared__ unsigned short Ws[32 * 512];
  const int tid = threadIdx.x;
  const int wave = tid >> 6, lane = tid & 63;
  const int wm = wave >> 1, wn = wave & 1;
  const int lr = lane & 15, lk = lane >> 4;
  const int m0 = blockIdx.y * 32, n0 = blockIdx.x * 32;
#pragma unroll
  for (int i = 0; i < 8; i++) {
    int c = tid + i * 256;
    int r = c >> 6, ql = c & 63;
    gld16(&A[(size_t)(m0 + r) * 512 + swz(ql, r) * 8], &As[(c & ~63) * 8]);
  }
#pragma unroll
  for (int i = 0; i < 8; i++) {
    int c = tid + i * 256;
    int r = c >> 6, ql = c & 63;
    gld16(&W[(size_t)(n0 + r) * 512 + swz(ql, r) * 8], &Ws[(c & ~63) * 8]);
  }
  __syncthreads();
  const int rA = wm * 16 + lr, rB = wn * 16 + lr;
  floatx4 ac[4];
#pragma unroll
  for (int j = 0; j < 4; j++) ac[j] = (floatx4){0.f, 0.f, 0.f, 0.f};
#pragma unroll
  for (int t = 0; t < 4; t++) {
#pragma unroll
    for (int j = 0; j < 4; j++) {
      int q = ((j * 128 + t * 32) >> 3) + lk;
      short8 av = *(const short8*)&As[rA * 512 + swz(q, rA) * 8];
      short8 bv = *(const short8*)&Ws[rB * 512 + swz(q, rB) * 8];
      ac[j] = __builtin_amdgcn_mfma_f32_16x16x32_bf16(av, bv, ac[j], 0, 0, 0);
    }
  }
  floatx4 acc = (ac[0] + ac[1]) + (ac[2] + ac[3]);
  int n = n0 + wn * 16 + lr;
  float bn = bias[n];
  // C/D layout (m89-verified): col = lane&15, row = (lane>>4)*4 + reg
#pragma unroll
  for (int r = 0; r < 4; r++) {
    int m = m0 + wm * 16 + lk * 4 + r;
    C[(size_t)m * 512 + n] = f2bf(elu1(acc[r] + bn));
  }
}

// ---- expert GEMM, all 8 experts/block, in-register gate combine ------------
// grid (16 n-tiles, 16 m-tiles, 2 k-halves), 48 KB LDS -> 3 blocks/CU.
// FROMP=0: A-panel staged from bf16 activations via gld16.
// FROMP=1: A-panel = elu(Pin[0]+Pin[1]) staged via VALU (fused reduce).
// Epilogue: kz==0 blocks fold the gate-blended beta into the partial, so
// Pout[0]+Pout[1] is the complete pre-activation.
template <int FROMP>
__global__ __launch_bounds__(256) void expert_gemm(
    const unsigned short* __restrict__ A,   // [512,512] bf16 (FROMP=0)
    const float* __restrict__ Pin,          // [2][512][512] (FROMP=1)
    const unsigned short* __restrict__ Wb,  // [E*512,512] bf16 alpha bank
    const float* __restrict__ g,            // [512,8] gates
    const float* __restrict__ beta,         // [E*512] fp32
    float* __restrict__ Pout) {             // [2][512][512] fp32 partials
  __shared__ unsigned short As[32 * 256];      // 16 KB
  __shared__ unsigned short Ws[2][32 * 256];   // 2 x 16 KB
  const int tid = threadIdx.x;
  const int wave = tid >> 6, lane = tid & 63;
  const int wm = wave >> 1, wn = wave & 1;
  const int lr = lane & 15, lk = lane >> 4;
  const int m0 = blockIdx.y * 32, n0 = blockIdx.x * 32;
  const int kz = blockIdx.z, kbeg = kz * 256;

  // stage A panel (32x256): 1024 chunks, 4 per thread
  if (FROMP) {
#pragma unroll
    for (int i = 0; i < 4; i++) {
      int c = tid + i * 256;
      int r = c >> 5, q = c & 31;
      const float* p0 = Pin + (size_t)(m0 + r) * 512 + kbeg + q * 8;
      const float* p1 = p0 + (size_t)Bq * Hq;
      float4 x0 = *(const float4*)p0, x1 = *(const float4*)(p0 + 4);
      float4 y0 = *(const float4*)p1, y1 = *(const float4*)(p1 + 4);
      short8 o;
      o[0] = (short)f2bf(elu1(x0.x + y0.x));
      o[1] = (short)f2bf(elu1(x0.y + y0.y));
      o[2] = (short)f2bf(elu1(x0.z + y0.z));
      o[3] = (short)f2bf(elu1(x0.w + y0.w));
      o[4] = (short)f2bf(elu1(x1.x + y1.x));
      o[5] = (short)f2bf(elu1(x1.y + y1.y));
      o[6] = (short)f2bf(elu1(x1.z + y1.z));
      o[7] = (short)f2bf(elu1(x1.w + y1.w));
      *(short8*)&As[(r * 32 + swz(q, r)) * 8] = o;
    }
  } else {
#pragma unroll
    for (int i = 0; i < 4; i++) {
      int c = tid + i * 256;
      int r = c >> 5, ql = c & 31;
      gld16(&A[(size_t)(m0 + r) * 512 + kbeg + swz(ql, r) * 8],
            &As[(c & ~63) * 8]);
    }
  }
  // stage W panel for expert 0 into buffer 0
#pragma unroll
  for (int i = 0; i < 4; i++) {
    int c = tid + i * 256;
    int r = c >> 5, ql = c & 31;
    gld16(&Wb[(size_t)(n0 + r) * 512 + kbeg + swz(ql, r) * 8],
          &Ws[0][(c & ~63) * 8]);
  }
  // gates for this lane's 4 output rows
  float g8[4][8];
#pragma unroll
  for (int r = 0; r < 4; r++) {
    int m = m0 + wm * 16 + lk * 4 + r;
    float4 ga = *(const float4*)&g[(size_t)m * 8];
    float4 gb = *(const float4*)&g[(size_t)m * 8 + 4];
    g8[r][0] = ga.x; g8[r][1] = ga.y; g8[r][2] = ga.z; g8[r][3] = ga.w;
    g8[r][4] = gb.x; g8[r][5] = gb.y; g8[r][6] = gb.z; g8[r][7] = gb.w;
  }

  const int rA = wm * 16 + lr, rB = wn * 16 + lr;
  floatx4 fin = {0.f, 0.f, 0.f, 0.f};
#pragma unroll
  for (int e = 0; e < 8; e++) {
    __syncthreads();  // drains A + W[e] staging; fences buffer reuse
    if (e < 7) {      // prefetch W[e+1]; overlaps with MFMA on W[e]
      const unsigned short* Wn = Wb + ((size_t)(e + 1) * 512 + n0) * 512 + kbeg;
#pragma unroll
      for (int i = 0; i < 4; i++) {
        int c = tid + i * 256;
        int r = c >> 5, ql = c & 31;
        gld16(&Wn[(size_t)r * 512 + swz(ql, r) * 8],
              &Ws[(e + 1) & 1][(c & ~63) * 8]);
      }
    }
    const unsigned short* wb = Ws[e & 1];
    floatx4 c0 = {0.f, 0.f, 0.f, 0.f}, c1 = {0.f, 0.f, 0.f, 0.f};
#pragma unroll
    for (int s = 0; s < 8; s++) {
      int q = s * 4 + lk;
      short8 av = *(const short8*)&As[rA * 256 + swz(q, rA) * 8];
      short8 bv = *(const short8*)&wb[rB * 256 + swz(q, rB) * 8];
      if (s & 1)
        c1 = __builtin_amdgcn_mfma_f32_16x16x32_bf16(av, bv, c1, 0, 0, 0);
      else
        c0 = __builtin_amdgcn_mfma_f32_16x16x32_bf16(av, bv, c0, 0, 0, 0);
    }
    floatx4 ae = c0 + c1;
#pragma unroll
    for (int r = 0; r < 4; r++) fin[r] += g8[r][e] * ae[r];
  }

  int n = n0 + wn * 16 + lr;
  if (kz == 0) {  // fold gate-blended beta into the kz=0 partial
    float bv[8];
#pragma unroll
    for (int e = 0; e < 8; e++) bv[e] = beta[e * 512 + n];
#pragma unroll
    for (int r = 0; r < 4; r++) {
      float bs = 0.f;
#pragma unroll
      for (int e = 0; e < 8; e++) bs += g8[r][e] * bv[e];
      fin[r] += bs;
    }
  }
  float* Po = Pout + (size_t)kz * Bq * Hq;
#pragma unroll
  for (int r = 0; r < 4; r++) {
    int m = m0 + wm * 16 + lk * 4 + r;
    Po[(size_t)m * 512 + n] = fin[r];
  }
}

// ---------------- gate logits + softmax (one wave per sample) ----------------
__global__ __launch_bounds__(64) void gate_kernel(
    const unsigned short* __restrict__ G1,  // [B,H] bf16
    const float* __restrict__ gw2,          // [E,H]
    const float* __restrict__ gb2,          // [E]
    float* __restrict__ g) {                // [B,E]
  int b = blockIdx.x;
  int lane = threadIdx.x;
  float xv[8];
#pragma unroll
  for (int t = 0; t < 8; t++) xv[t] = bf2f(G1[(size_t)b * Hq + t * 64 + lane]);
  float le[Eq];
#pragma unroll
  for (int e = 0; e < Eq; e++) {
    float p = 0.f;
#pragma unroll
    for (int t = 0; t < 8; t++)
      p += xv[t] * gw2[(size_t)e * Hq + t * 64 + lane];
#pragma unroll
    for (int o = 32; o > 0; o >>= 1) p += __shfl_xor(p, o);
    le[e] = p + gb2[e];
  }
  float m = le[0];
#pragma unroll
  for (int e = 1; e < Eq; e++) m = fmaxf(m, le[e]);
  float s = 0.f;
#pragma unroll
  for (int e = 0; e < Eq; e++) {
    le[e] = __expf(le[e] - m);
    s += le[e];
  }
  float inv = 1.f / s;
  if (lane == 0) {
#pragma unroll
    for (int e = 0; e < Eq; e++) g[(size_t)b * Eq + e] = le[e] * inv;
  }
}

// ---------- final reduce: out = P[0] + P[1] (beta already folded) -----------
__global__ __launch_bounds__(256) void reduce_final(
    const float* __restrict__ P, float* __restrict__ outf) {
  int idx = blockIdx.x * 256 + threadIdx.x;  // over B*H/4
  const float4 v0 = ((const float4*)P)[idx];
  const float4 v1 = ((const float4*)(P + (size_t)Bq * Hq))[idx];
  float4 s = {v0.x + v1.x, v0.y + v1.y, v0.z + v1.z, v0.w + v1.w};
  ((float4*)outf)[idx] = s;
}

extern "C" void kernel_launch(void* const* d_in, const int* in_sizes, int n_in,
                              void* d_out, int out_size, void* d_ws,
                              size_t ws_size, hipStream_t stream) {
  const float* x = (const float*)d_in[0];
  const float* gw0 = (const float*)d_in[1];
  const float* gb0 = (const float*)d_in[2];
  const float* gw1 = (const float*)d_in[3];
  const float* gb1 = (const float*)d_in[4];
  const float* gw2 = (const float*)d_in[5];
  const float* gb2 = (const float*)d_in[6];
  const float* alpha0 = (const float*)d_in[7];
  const float* beta0 = (const float*)d_in[8];
  const float* alpha1 = (const float*)d_in[9];
  const float* beta1 = (const float*)d_in[10];
  const float* alpha2 = (const float*)d_in[11];
  const float* beta2 = (const float*)d_in[12];
  float* out = (float*)d_out;

  char* ws = (char*)d_ws;
  auto alloc = [&](size_t bytes) {
    char* p = ws;
    ws += (bytes + 255) & ~(size_t)255;
    return p;
  };
  unsigned short* xb = (unsigned short*)alloc((size_t)Bq * Fq * 2);
  unsigned short* gw0b = (unsigned short*)alloc((size_t)Hq * Fq * 2);
  unsigned short* gw1b = (unsigned short*)alloc((size_t)Hq * Hq * 2);
  unsigned short* a0b = (unsigned short*)alloc((size_t)Eq * Hq * Fq * 2);
  unsigned short* a1b = (unsigned short*)alloc((size_t)Eq * Hq * Hq * 2);
  unsigned short* a2b = (unsigned short*)alloc((size_t)Eq * Oq * Hq * 2);
  unsigned short* G0b = (unsigned short*)alloc((size_t)Bq * Hq * 2);
  unsigned short* G1b = (unsigned short*)alloc((size_t)Bq * Hq * 2);
  float* gates = (float*)alloc((size_t)Bq * Eq * 4);
  float* P1 = (float*)alloc((size_t)2 * Bq * Hq * 4);
  float* P2 = (float*)alloc((size_t)2 * Bq * Hq * 4);

  // 1) all fp32->bf16 converts in one launch
  {
    int nb = (Eq * Hq * Fq) / 4, ns = (Bq * Fq) / 4;
    int total = 3 * nb + 3 * ns;
    cvt6_kernel<<<(total + 255) / 256, 256, 0, stream>>>(
        alpha0, alpha1, alpha2, a0b, a1b, a2b, x, gw0, gw1, xb, gw0b, gw1b,
        nb, ns);
  }

  // 2) gating MLP: single-barrier 32x32 tiles, 256 blocks each
  dim3 gg(16, 16);
  gating_gemm<<<gg, 256, 0, stream>>>(xb, gw0b, gb0, G0b);
  gating_gemm<<<gg, 256, 0, stream>>>(G0b, gw1b, gb1, G1b);

  // 3) gate logits + softmax
  gate_kernel<<<Bq, 64, 0, stream>>>(G1b, gw2, gb2, gates);

  // 4) experts: layer GEMMs with fused reduce-in-staging; one final reduce
  dim3 ge(16, 16, 2);
  expert_gemm<0><<<ge, 256, 0, stream>>>(xb, nullptr, a0b, gates, beta0, P1);
  expert_gemm<1><<<ge, 256, 0, stream>>>(nullptr, P1, a1b, gates, beta1, P2);
  expert_gemm<1><<<ge, 256, 0, stream>>>(nullptr, P2, a2b, gates, beta2, P1);
  reduce_final<<<(Bq * Hq / 4) / 256, 256, 0, stream>>>(P1, out);
}